// Round 12
// baseline (123.160 us; speedup 1.0000x reference)
//
#include <hip/hip_runtime.h>
#include <hip/hip_bf16.h>

#define HEADS 16
#define HDIM 64
#define EMB 1024
#define NBATCH 4
#define SEQ 2048
#define NT (SEQ/64)

typedef __bf16 bf16x8 __attribute__((ext_vector_type(8)));
typedef __bf16 bf16x4 __attribute__((ext_vector_type(4)));
typedef float f32x4 __attribute__((ext_vector_type(4)));
typedef float f32x16 __attribute__((ext_vector_type(16)));

#define Z16 {0.f,0.f,0.f,0.f,0.f,0.f,0.f,0.f,0.f,0.f,0.f,0.f,0.f,0.f,0.f,0.f}

static __device__ __forceinline__ bf16x8 load_cvt8(const float* __restrict__ p) {
    float4 a = *reinterpret_cast<const float4*>(p);
    float4 b = *reinterpret_cast<const float4*>(p + 4);
    bf16x8 r;
    r[0] = (__bf16)a.x; r[1] = (__bf16)a.y; r[2] = (__bf16)a.z; r[3] = (__bf16)a.w;
    r[4] = (__bf16)b.x; r[5] = (__bf16)b.y; r[6] = (__bf16)b.z; r[7] = (__bf16)b.w;
    return r;
}

static __device__ __forceinline__ unsigned cvt_pk_bf16(float a, float b) {
    unsigned d;
    asm("v_cvt_pk_bf16_f32 %0, %1, %2" : "=v"(d) : "v"(a), "v"(b));
    return d;
}

static __device__ __forceinline__ void pl_swap(unsigned &a, unsigned &b) {
#if __has_builtin(__builtin_amdgcn_permlane32_swap)
    auto r = __builtin_amdgcn_permlane32_swap((int)a, (int)b, false, false);
    a = (unsigned)r[0]; b = (unsigned)r[1];
#else
    asm("v_permlane32_swap_b32 %0, %1" : "+v"(a), "+v"(b));
#endif
}

// ---------------------------------------------------------------------------
// Kernel 1: QKV projection + Wo convert. grid=(SEQ/64, N*H, 4), 256 thr.
// ---------------------------------------------------------------------------
__global__ __launch_bounds__(256) void proj_kernel(
    const float* __restrict__ keys, const float* __restrict__ query,
    const float* __restrict__ values,
    const float* __restrict__ Wk, const float* __restrict__ Wq,
    const float* __restrict__ Wv, const float* __restrict__ Wo,
    __bf16* __restrict__ qb, __bf16* __restrict__ kb, __bf16* __restrict__ vtb,
    __bf16* __restrict__ wob)
{
    int t = threadIdx.x;
    int which = blockIdx.z;

    if (which == 3) {
        int idx = blockIdx.y*gridDim.x + blockIdx.x;
        if (idx < EMB*EMB/4/256) {
            int i = idx*256 + t;
            float4 v = reinterpret_cast<const float4*>(Wo)[i];
            bf16x4 r;
            r[0] = (__bf16)v.x; r[1] = (__bf16)v.y; r[2] = (__bf16)v.z; r[3] = (__bf16)v.w;
            reinterpret_cast<bf16x4*>(wob)[i] = r;
        }
        return;
    }

    __shared__ __align__(16) __bf16 vlds[64][72];

    int wave = t >> 6, lane = t & 63;
    int l16 = lane & 15, g = lane >> 4;
    int sblk = blockIdx.x, nh = blockIdx.y;
    int n = nh >> 4, h = nh & 15;

    const float* X = (which == 0) ? query : (which == 1) ? keys : values;
    const float* W = (which == 0) ? Wq    : (which == 1) ? Wk   : Wv;
    const float wsc = (which == 0) ? (1.44269504088896f / 512.f) : 1.0f;

    {
        const float* wp = W + t*16;
        int row = t >> 2, c0 = (t & 3)*16;
#pragma unroll
        for (int q4 = 0; q4 < 4; ++q4) {
            float4 v = *reinterpret_cast<const float4*>(wp + q4*4);
            vlds[row][c0 + q4*4 + 0] = (__bf16)(v.x*wsc);
            vlds[row][c0 + q4*4 + 1] = (__bf16)(v.y*wsc);
            vlds[row][c0 + q4*4 + 2] = (__bf16)(v.z*wsc);
            vlds[row][c0 + q4*4 + 3] = (__bf16)(v.w*wsc);
        }
    }
    __syncthreads();

    bf16x8 wf[4][2];
#pragma unroll
    for (int j = 0; j < 4; ++j)
#pragma unroll
        for (int kc = 0; kc < 2; ++kc)
            wf[j][kc] = *reinterpret_cast<const bf16x8*>(&vlds[j*16 + l16][kc*32 + g*8]);

    int s0 = sblk*64 + wave*16;
    const float* xp = X + ((size_t)(n*SEQ + s0 + l16)*HEADS + h)*64;
    bf16x8 af0 = load_cvt8(xp + g*8);
    bf16x8 af1 = load_cvt8(xp + 32 + g*8);

    __syncthreads();

    f32x4 acc[4];
#pragma unroll
    for (int j = 0; j < 4; ++j) acc[j] = (f32x4){0.f, 0.f, 0.f, 0.f};
#pragma unroll
    for (int j = 0; j < 4; ++j) {
        acc[j] = __builtin_amdgcn_mfma_f32_16x16x32_bf16(af0, wf[j][0], acc[j], 0, 0, 0);
        acc[j] = __builtin_amdgcn_mfma_f32_16x16x32_bf16(af1, wf[j][1], acc[j], 0, 0, 0);
    }

#pragma unroll
    for (int j = 0; j < 4; ++j)
#pragma unroll
        for (int r = 0; r < 4; ++r)
            vlds[wave*16 + g*4 + r][j*16 + l16] = (__bf16)acc[j][r];
    __syncthreads();

    if (which < 2) {
        int row = t >> 2, seg = t & 3;
        __bf16* dst = (which == 0 ? qb : kb) + (size_t)nh*SEQ*64
                      + (size_t)(sblk*64 + row)*64 + seg*16;
        *reinterpret_cast<int4*>(dst)     = *reinterpret_cast<const int4*>(&vlds[row][seg*16]);
        *reinterpret_cast<int4*>(dst + 8) = *reinterpret_cast<const int4*>(&vlds[row][seg*16 + 8]);
    } else {
        int d = t & 63, sc4 = t >> 6;
        alignas(16) __bf16 tmp[16];
#pragma unroll
        for (int i = 0; i < 16; ++i) tmp[i] = vlds[sc4*16 + i][d];
        __bf16* dst = vtb + ((size_t)nh*64 + d)*SEQ + sblk*64 + sc4*16;
        *reinterpret_cast<int4*>(dst)     = *reinterpret_cast<const int4*>(tmp);
        *reinterpret_cast<int4*>(dst + 8) = *reinterpret_cast<const int4*>(tmp + 8);
    }
}

// ---------------------------------------------------------------------------
// Kernel 2: flash attention, half-tile software pipeline (verified r9 best:
// attn 72.7us). Per tile t (one unfenced region):
//   QKT(t,sb1)->y || SMPV(t,sb0 from X) || QKT(t+1,sb0)->Z || SMPV(t,sb1)
// Persistent-zero C-in on fresh QK^T chains. 4-deep LDS ring (64KB), one
// barrier/iter, counted vmcnt. X/Z ping-pong via 2x unrolled loop.
// grid = 512, block = 256 (4 waves, 64 q each), 2 blocks/CU.
// SESSION LEDGER (do not retry without new evidence):
//  - r7 forced sched_group interleave: -9% (T19 null-as-graft holds)
//  - r8 wave-parity stagger: FAILED correctness (unexplained)
//  - r10/r11 K-split (bf16 & fp16 partials): FAILED at ~6e-3, format-
//    independent -> structural, bug not found by 3x mapping audit.
// ---------------------------------------------------------------------------
__global__ __launch_bounds__(256, 2) void attn_kernel(
    const __bf16* __restrict__ qb, const __bf16* __restrict__ kb,
    const __bf16* __restrict__ vtb, __bf16* __restrict__ ob)
{
    __shared__ __align__(16) char smem[65536];

    int t = threadIdx.x;
    int wave = t >> 6, lane = t & 63;
    int l31 = lane & 31, hi = lane >> 5;

    int id = blockIdx.x;
    int qblk = id >> 6;
    int nh = (id & 7)*8 + ((id >> 3) & 7);
    int n = nh >> 4, h = nh & 15;

    const __bf16* Qp = qb  + (size_t)nh*SEQ*64;
    const __bf16* Kp = kb  + (size_t)nh*SEQ*64;
    const __bf16* Vp = vtb + (size_t)nh*64*SEQ;

    int st_row[2], st_col[2];
#pragma unroll
    for (int i = 0; i < 2; ++i) {
        int o = wave*2048 + i*1024 + lane*16;
        st_row[i] = o >> 7;
        st_col[i] = (o & 127) ^ ((st_row[i] & 7) << 4);
    }

    int q0 = qblk*256 + wave*64;
    const __bf16* qp = Qp + (size_t)(q0 + l31)*64 + hi*8;
    bf16x8 qfA[4], qfB[4];
#pragma unroll
    for (int i = 0; i < 4; ++i) {
        qfA[i] = *reinterpret_cast<const bf16x8*>(qp + i*16);
        qfB[i] = *reinterpret_cast<const bf16x8*>(qp + 2048 + i*16);
    }

    const f32x16 vzero = Z16;   // persistent zero C-in for fresh MFMA chains
    f32x16 oaccA0 = Z16, oaccA1 = Z16, oaccB0 = Z16, oaccB1 = Z16;
    float lsA0 = 0.f, lsA1 = 0.f, lsA2 = 0.f, lsA3 = 0.f;
    float lsB0 = 0.f, lsB1 = 0.f, lsB2 = 0.f, lsB3 = 0.f;

    const char* vb_;
    int swz = (l31 & 7) << 4;

#define STAGE_TILE(gbase, stride, ldsoff)                                          \
    {                                                                              \
        _Pragma("unroll")                                                          \
        for (int i_ = 0; i_ < 2; ++i_) {                                           \
            const char* g_ = (const char*)((gbase) + (size_t)st_row[i_]*(stride))  \
                             + st_col[i_];                                         \
            __builtin_amdgcn_global_load_lds(                                      \
                (const __attribute__((address_space(1))) void*)g_,                 \
                (__attribute__((address_space(3))) void*)(smem + (ldsoff)          \
                    + wave*2048 + i_*1024), 16, 0, 0);                             \
        }                                                                          \
    }

#define STAGE(s)                                                                   \
    {                                                                              \
        int b_ = (s) & 3;                                                          \
        STAGE_TILE(Kp + (size_t)(s)*64*64, 64, b_*8192);                           \
        STAGE_TILE(Vp + (size_t)(s)*64, SEQ, 32768 + b_*8192);                     \
    }

// QK^T half-tile: k-rows RO..RO+31 of buffer KBP, 8 MFMAs on 2 chains.
// First MFMA of each chain uses vzero C-in (no zero-init movs needed).
#define QKTH(KBP, RO, EA, EB)                                                      \
    {                                                                              \
        bf16x8 kf0_ = *(const bf16x8*)((KBP) + ((RO) + l31)*128 + ((0*32 + hi*16) ^ swz)); \
        bf16x8 kf1_ = *(const bf16x8*)((KBP) + ((RO) + l31)*128 + ((1*32 + hi*16) ^ swz)); \
        bf16x8 kf2_ = *(const bf16x8*)((KBP) + ((RO) + l31)*128 + ((2*32 + hi*16) ^ swz)); \
        bf16x8 kf3_ = *(const bf16x8*)((KBP) + ((RO) + l31)*128 + ((3*32 + hi*16) ^ swz)); \
        EA = __builtin_amdgcn_mfma_f32_32x32x16_bf16(kf0_, qfA[0], vzero, 0, 0, 0); \
        EB = __builtin_amdgcn_mfma_f32_32x32x16_bf16(kf0_, qfB[0], vzero, 0, 0, 0); \
        EA = __builtin_amdgcn_mfma_f32_32x32x16_bf16(kf1_, qfA[1], EA, 0, 0, 0);   \
        EB = __builtin_amdgcn_mfma_f32_32x32x16_bf16(kf1_, qfB[1], EB, 0, 0, 0);   \
        EA = __builtin_amdgcn_mfma_f32_32x32x16_bf16(kf2_, qfA[2], EA, 0, 0, 0);   \
        EB = __builtin_amdgcn_mfma_f32_32x32x16_bf16(kf2_, qfB[2], EB, 0, 0, 0);   \
        EA = __builtin_amdgcn_mfma_f32_32x32x16_bf16(kf3_, qfA[3], EA, 0, 0, 0);   \
        EB = __builtin_amdgcn_mfma_f32_32x32x16_bf16(kf3_, qfB[3], EB, 0, 0, 0);   \
    }

#define MAKE_PU_FAST(E, P, PU0, PU1)                                               \
    {                                                                              \
        _Pragma("unroll")                                                          \
        for (int i_ = 0; i_ < 16; ++i_)                                            \
            P[i_] = __builtin_amdgcn_exp2f(E[i_]);                                 \
        unsigned w00 = cvt_pk_bf16(P[0],  P[1]);                                   \
        unsigned w01 = cvt_pk_bf16(P[2],  P[3]);                                   \
        unsigned w10 = cvt_pk_bf16(P[4],  P[5]);                                   \
        unsigned w11 = cvt_pk_bf16(P[6],  P[7]);                                   \
        unsigned w20 = cvt_pk_bf16(P[8],  P[9]);                                   \
        unsigned w21 = cvt_pk_bf16(P[10], P[11]);                                  \
        unsigned w30 = cvt_pk_bf16(P[12], P[13]);                                  \
        unsigned w31 = cvt_pk_bf16(P[14], P[15]);                                  \
        pl_swap(w00, w10); pl_swap(w01, w11);                                      \
        pl_swap(w20, w30); pl_swap(w21, w31);                                      \
        PU0.u[0] = w00; PU0.u[1] = w01; PU0.u[2] = w10; PU0.u[3] = w11;            \
        PU1.u[0] = w20; PU1.u[1] = w21; PU1.u[2] = w30; PU1.u[3] = w31;            \
    }

#define LS_ACC(P, LS0, LS1, LS2, LS3)                                              \
    {                                                                              \
        LS0 += P[0] + P[4];  LS1 += P[1] + P[5];                                   \
        LS2 += P[2] + P[6];  LS3 += P[3] + P[7];                                   \
        LS0 += P[8] + P[12]; LS1 += P[9] + P[13];                                  \
        LS2 += P[10] + P[14]; LS3 += P[11] + P[15];                                \
    }

#define SMPV(SB, EA, EB)                                                           \
    {                                                                              \
        union { unsigned u[4]; bf16x8 v; } puA0, puA1, puB0, puB1;                 \
        float pA_[16], pB_[16];                                                    \
        MAKE_PU_FAST(EA, pA_, puA0, puA1)                                          \
        MAKE_PU_FAST(EB, pB_, puB0, puB1)                                          \
        bf16x8 v00 = *(const bf16x8*)(vb_ + (l31)*128      + (((SB)*64 +  0 + hi*16) ^ swz)); \
        bf16x8 v01 = *(const bf16x8*)(vb_ + (l31)*128      + (((SB)*64 + 32 + hi*16) ^ swz)); \
        bf16x8 v10 = *(const bf16x8*)(vb_ + (32 + l31)*128 + (((SB)*64 +  0 + hi*16) ^ swz)); \
        bf16x8 v11 = *(const bf16x8*)(vb_ + (32 + l31)*128 + (((SB)*64 + 32 + hi*16) ^ swz)); \
        oaccA0 = __builtin_amdgcn_mfma_f32_32x32x16_bf16(v00, puA0.v, oaccA0, 0, 0, 0); \
        oaccA1 = __builtin_amdgcn_mfma_f32_32x32x16_bf16(v10, puA0.v, oaccA1, 0, 0, 0); \
        oaccB0 = __builtin_amdgcn_mfma_f32_32x32x16_bf16(v00, puB0.v, oaccB0, 0, 0, 0); \
        oaccB1 = __builtin_amdgcn_mfma_f32_32x32x16_bf16(v10, puB0.v, oaccB1, 0, 0, 0); \
        oaccA0 = __builtin_amdgcn_mfma_f32_32x32x16_bf16(v01, puA1.v, oaccA0, 0, 0, 0); \
        oaccA1 = __builtin_amdgcn_mfma_f32_32x32x16_bf16(v11, puA1.v, oaccA1, 0, 0, 0); \
        oaccB0 = __builtin_amdgcn_mfma_f32_32x32x16_bf16(v01, puB1.v, oaccB0, 0, 0, 0); \
        oaccB1 = __builtin_amdgcn_mfma_f32_32x32x16_bf16(v11, puB1.v, oaccB1, 0, 0, 0); \
        LS_ACC(pA_, lsA0, lsA1, lsA2, lsA3)                                        \
        LS_ACC(pB_, lsB0, lsB1, lsB2, lsB3)                                        \
    }

// One pipelined tile: consume e(T,sb0) from (XA,XB); produce e(T+1,sb0) into
// (ZA,ZB).  VMN = vmcnt after staging.  DO_STAGE: stage tile T+2.
#define BODY(T, XA, XB, ZA, ZB, DO_STAGE, VMN)                                     \
    {                                                                              \
        if (DO_STAGE) STAGE((T) + 2);                                              \
        asm volatile("s_waitcnt vmcnt(" #VMN ")" ::: "memory");                    \
        __builtin_amdgcn_s_barrier();                                              \
        __builtin_amdgcn_sched_barrier(0);                                         \
        const char* kcur_ = smem + ((T) & 3)*8192;                                 \
        const char* knxt_ = smem + (((T) + 1) & 3)*8192;                           \
        vb_ = smem + 32768 + ((T) & 3)*8192;                                       \
        f32x16 yA_, yB_;                                                           \
        QKTH(kcur_, 32, yA_, yB_)                                                  \
        SMPV(0, XA, XB)                                                            \
        QKTH(knxt_, 0, ZA, ZB)                                                     \
        SMPV(1, yA_, yB_)                                                          \
    }

    // prologue: stage tiles 0,1; then e(0,sb0) -> X
    STAGE(0);
    STAGE(1);
    asm volatile("s_waitcnt vmcnt(4)" ::: "memory");
    __builtin_amdgcn_s_barrier();
    __builtin_amdgcn_sched_barrier(0);
    f32x16 xA, xB;
    f32x16 zA, zB;
    QKTH(smem + 0, 0, xA, xB)

    // main: t = 0..29 in ping-pong pairs (always stages t+2 <= 31)
    for (int p = 0; p < 15; ++p) {
        int t0 = 2*p;
        BODY(t0,     xA, xB, zA, zB, 1, 4)
        BODY(t0 + 1, zA, zB, xA, xB, 1, 4)
    }
    // t = 30: no stage (t+2 == 32), drain to confirm tile 31
    BODY(30, xA, xB, zA, zB, 0, 0)

    // tail t = 31: consume Z (= e(31,sb0)), compute sb1, no next-QKT
    {
        asm volatile("s_waitcnt vmcnt(0)" ::: "memory");
        __builtin_amdgcn_s_barrier();
        __builtin_amdgcn_sched_barrier(0);
        const char* kcur_ = smem + (31 & 3)*8192;
        vb_ = smem + 32768 + (31 & 3)*8192;
        f32x16 yA_, yB_;
        QKTH(kcur_, 32, yA_, yB_)
        SMPV(0, zA, zB)
        SMPV(1, yA_, yB_)
    }

    float lA = (lsA0 + lsA1) + (lsA2 + lsA3);
    float totA = lA + __shfl_xor(lA, 32);
    float invA = 1.f / totA;
    float lB = (lsB0 + lsB1) + (lsB2 + lsB3);
    float totB = lB + __shfl_xor(lB, 32);
    float invB = 1.f / totB;

    __bf16* opA = ob + (size_t)(n*SEQ + q0 + l31)*EMB + h*64;
    __bf16* opB = opA + (size_t)32*EMB;
#pragma unroll
    for (int j = 0; j < 4; ++j)
#pragma unroll
        for (int c = 0; c < 4; ++c) {
            int d_ = c + 8*j + 4*hi;
            opA[d_]      = (__bf16)(oaccA0[4*j + c] * invA);
            opA[32 + d_] = (__bf16)(oaccA1[4*j + c] * invA);
            opB[d_]      = (__bf16)(oaccB0[4*j + c] * invB);
            opB[32 + d_] = (__bf16)(oaccB1[4*j + c] * invB);
        }
#undef STAGE_TILE
#undef STAGE
#undef QKTH
#undef MAKE_PU_FAST
#undef LS_ACC
#undef SMPV
#undef BODY
}

// ---------------------------------------------------------------------------
// Kernel 3: out = O @ Wo^T + bo. m97-pattern tiled GEMM (unchanged).
// ---------------------------------------------------------------------------
__global__ __launch_bounds__(256, 2) void out_gemm_kernel(
    const __bf16* __restrict__ ob, const __bf16* __restrict__ wob,
    const float* __restrict__ bo, float* __restrict__ out)
{
    __shared__ __align__(16) char smem[65536];

    int t = threadIdx.x;
    int wave = t >> 6, lane = t & 63;
    int l16 = lane & 15, g = lane >> 4;

    int bid = blockIdx.x;
    int swz = (bid & 7)*64 + (bid >> 3);
    int mb = (swz >> 3)*128;
    int nb = (swz & 7)*128;
    int wr = wave >> 1, wc = wave & 1;

    int st_row[4], st_col[4];
#pragma unroll
    for (int i = 0; i < 4; ++i) {
        int o = i*4096 + wave*1024 + lane*16;
        st_row[i] = o >> 7;
        st_col[i] = (o & 127) ^ ((st_row[i] & 7) << 4);
    }

#define G_STAGE(kt, buf)                                                            \
    {                                                                               \
        _Pragma("unroll")                                                           \
        for (int i_ = 0; i_ < 4; ++i_) {                                            \
            const char* ga_ = (const char*)(ob + (size_t)(mb + st_row[i_])*EMB      \
                                + (kt)*64) + st_col[i_];                            \
            __builtin_amdgcn_global_load_lds(                                       \
                (const __attribute__((address_space(1))) void*)ga_,                 \
                (__attribute__((address_space(3))) void*)(smem + (buf)*16384        \
                    + i_*4096 + wave*1024), 16, 0, 0);                              \
            const char* gb_ = (const char*)(wob + (size_t)(nb + st_row[i_])*EMB     \
                                + (kt)*64) + st_col[i_];                            \
            __builtin_amdgcn_global_load_lds(                                       \
                (const __attribute__((address_space(1))) void*)gb_,                 \
                (__attribute__((address_space(3))) void*)(smem + 32768 + (buf)*16384\
                    + i_*4096 + wave*1024), 16, 0, 0);                              \
        }                                                                           \
    }

    f32x4 acc[4][4];
#pragma unroll
    for (int m = 0; m < 4; ++m)
#pragma unroll
        for (int n = 0; n < 4; ++n) acc[m][n] = (f32x4){0.f, 0.f, 0.f, 0.f};

    G_STAGE(0, 0);
    __syncthreads();

    int cur = 0;
    for (int kt = 0; kt < EMB/64; ++kt) {
        if (kt + 1 < EMB/64) G_STAGE(kt + 1, cur ^ 1);

        const char* ab_ = smem + cur*16384;
        const char* bb_ = smem + 32768 + cur*16384;

        bf16x8 af[4][2], bf[4][2];
#pragma unroll
        for (int m = 0; m < 4; ++m) {
            int row = wr*64 + m*16 + l16, s = (row & 7) << 4;
            af[m][0] = *(const bf16x8*)(ab_ + row*128 + ((g*16) ^ s));
            af[m][1] = *(const bf16x8*)(ab_ + row*128 + ((64 + g*16) ^ s));
        }
#pragma unroll
        for (int n = 0; n < 4; ++n) {
            int row = wc*64 + n*16 + l16, s = (row & 7) << 4;
            bf[n][0] = *(const bf16x8*)(bb_ + row*128 + ((g*16) ^ s));
            bf[n][1] = *(const bf16x8*)(bb_ + row*128 + ((64 + g*16) ^ s));
        }

        __builtin_amdgcn_s_setprio(1);
#pragma unroll
        for (int m = 0; m < 4; ++m)
#pragma unroll
            for (int n = 0; n < 4; ++n) {
                acc[m][n] = __builtin_amdgcn_mfma_f32_16x16x32_bf16(af[m][0], bf[n][0], acc[m][n], 0, 0, 0);
                acc[m][n] = __builtin_amdgcn_mfma_f32_16x16x32_bf16(af[m][1], bf[n][1], acc[m][n], 0, 0, 0);
            }
        __builtin_amdgcn_s_setprio(0);

        __syncthreads();
        cur ^= 1;
    }

#pragma unroll
    for (int n = 0; n < 4; ++n) {
        int col = nb + wc*64 + n*16 + l16;
        float bias = bo[col];
#pragma unroll
        for (int m = 0; m < 4; ++m) {
            int rowb = mb + wr*64 + m*16 + g*4;
#pragma unroll
            for (int r = 0; r < 4; ++r)
                out[(size_t)(rowb + r)*EMB + col] = acc[m][n][r] + bias;
        }
    }
#undef G_STAGE
}

extern "C" void kernel_launch(void* const* d_in, const int* in_sizes, int n_in,
                              void* d_out, int out_size, void* d_ws, size_t ws_size,
                              hipStream_t stream) {
    const float* keys   = (const float*)d_in[0];
    const float* query  = (const float*)d_in[1];
    const float* values = (const float*)d_in[2];
    const float* Wk     = (const float*)d_in[3];
    const float* Wq     = (const float*)d_in[4];
    const float* Wv     = (const float*)d_in[5];
    const float* Wo     = (const float*)d_in[6];
    const float* bo     = (const float*)d_in[7];
    float* out = (float*)d_out;

    char* ws = (char*)d_ws;
    __bf16* qb  = (__bf16*)(ws);                              // 16 MB [n,h,s,64] (pre-scaled)
    __bf16* kb  = (__bf16*)(ws + (size_t)16*1024*1024);       // 16 MB [n,h,s,64]
    __bf16* vtb = (__bf16*)(ws + (size_t)32*1024*1024);       // 16 MB [n,h,64,s]
    __bf16* ob  = (__bf16*)(ws + (size_t)48*1024*1024);       // 16 MB [n*s, 1024]
    __bf16* wob = (__bf16*)(ws + (size_t)64*1024*1024);       //  2 MB [1024,1024]

    hipLaunchKernelGGL(proj_kernel, dim3(SEQ/64, NBATCH*HEADS, 4), dim3(256), 0, stream,
                       keys, query, values, Wk, Wq, Wv, Wo, qb, kb, vtb, wob);
    hipLaunchKernelGGL(attn_kernel, dim3(512), dim3(256), 0, stream,
                       qb, kb, vtb, ob);
    hipLaunchKernelGGL(out_gemm_kernel, dim3(512), dim3(256), 0, stream,
                       ob, wob, bo, out);
}

// Round 14
// 122.662 us; speedup vs baseline: 1.0041x; 1.0041x over previous
//
#include <hip/hip_runtime.h>
#include <hip/hip_bf16.h>

#define HEADS 16
#define HDIM 64
#define EMB 1024
#define NBATCH 4
#define SEQ 2048
#define NT (SEQ/64)

typedef __bf16 bf16x8 __attribute__((ext_vector_type(8)));
typedef __bf16 bf16x4 __attribute__((ext_vector_type(4)));
typedef float f32x4 __attribute__((ext_vector_type(4)));
typedef float f32x16 __attribute__((ext_vector_type(16)));

#define Z16 {0.f,0.f,0.f,0.f,0.f,0.f,0.f,0.f,0.f,0.f,0.f,0.f,0.f,0.f,0.f,0.f}

static __device__ __forceinline__ bf16x8 load_cvt8(const float* __restrict__ p) {
    float4 a = *reinterpret_cast<const float4*>(p);
    float4 b = *reinterpret_cast<const float4*>(p + 4);
    bf16x8 r;
    r[0] = (__bf16)a.x; r[1] = (__bf16)a.y; r[2] = (__bf16)a.z; r[3] = (__bf16)a.w;
    r[4] = (__bf16)b.x; r[5] = (__bf16)b.y; r[6] = (__bf16)b.z; r[7] = (__bf16)b.w;
    return r;
}

static __device__ __forceinline__ unsigned cvt_pk_bf16(float a, float b) {
    unsigned d;
    asm("v_cvt_pk_bf16_f32 %0, %1, %2" : "=v"(d) : "v"(a), "v"(b));
    return d;
}

static __device__ __forceinline__ void pl_swap(unsigned &a, unsigned &b) {
#if __has_builtin(__builtin_amdgcn_permlane32_swap)
    auto r = __builtin_amdgcn_permlane32_swap((int)a, (int)b, false, false);
    a = (unsigned)r[0]; b = (unsigned)r[1];
#else
    asm("v_permlane32_swap_b32 %0, %1" : "+v"(a), "+v"(b));
#endif
}

// ---------------------------------------------------------------------------
// Kernel 1: QKV projection + Wo convert. grid=(SEQ/64, N*H, 4), 256 thr.
// z==0: q = (query @ Wq^T) * log2e/512 -> qb; z==1: k; z==2: v -> vtb (transp)
// z==3: Wo fp32->bf16.
// ---------------------------------------------------------------------------
__global__ __launch_bounds__(256) void proj_kernel(
    const float* __restrict__ keys, const float* __restrict__ query,
    const float* __restrict__ values,
    const float* __restrict__ Wk, const float* __restrict__ Wq,
    const float* __restrict__ Wv, const float* __restrict__ Wo,
    __bf16* __restrict__ qb, __bf16* __restrict__ kb, __bf16* __restrict__ vtb,
    __bf16* __restrict__ wob)
{
    int t = threadIdx.x;
    int which = blockIdx.z;

    if (which == 3) {
        int idx = blockIdx.y*gridDim.x + blockIdx.x;
        if (idx < EMB*EMB/4/256) {
            int i = idx*256 + t;
            float4 v = reinterpret_cast<const float4*>(Wo)[i];
            bf16x4 r;
            r[0] = (__bf16)v.x; r[1] = (__bf16)v.y; r[2] = (__bf16)v.z; r[3] = (__bf16)v.w;
            reinterpret_cast<bf16x4*>(wob)[i] = r;
        }
        return;
    }

    __shared__ __align__(16) __bf16 vlds[64][72];

    int wave = t >> 6, lane = t & 63;
    int l16 = lane & 15, g = lane >> 4;
    int sblk = blockIdx.x, nh = blockIdx.y;
    int n = nh >> 4, h = nh & 15;

    const float* X = (which == 0) ? query : (which == 1) ? keys : values;
    const float* W = (which == 0) ? Wq    : (which == 1) ? Wk   : Wv;
    const float wsc = (which == 0) ? (1.44269504088896f / 512.f) : 1.0f;

    {
        const float* wp = W + t*16;
        int row = t >> 2, c0 = (t & 3)*16;
#pragma unroll
        for (int q4 = 0; q4 < 4; ++q4) {
            float4 v = *reinterpret_cast<const float4*>(wp + q4*4);
            vlds[row][c0 + q4*4 + 0] = (__bf16)(v.x*wsc);
            vlds[row][c0 + q4*4 + 1] = (__bf16)(v.y*wsc);
            vlds[row][c0 + q4*4 + 2] = (__bf16)(v.z*wsc);
            vlds[row][c0 + q4*4 + 3] = (__bf16)(v.w*wsc);
        }
    }
    __syncthreads();

    bf16x8 wf[4][2];
#pragma unroll
    for (int j = 0; j < 4; ++j)
#pragma unroll
        for (int kc = 0; kc < 2; ++kc)
            wf[j][kc] = *reinterpret_cast<const bf16x8*>(&vlds[j*16 + l16][kc*32 + g*8]);

    int s0 = sblk*64 + wave*16;
    const float* xp = X + ((size_t)(n*SEQ + s0 + l16)*HEADS + h)*64;
    bf16x8 af0 = load_cvt8(xp + g*8);
    bf16x8 af1 = load_cvt8(xp + 32 + g*8);

    __syncthreads();

    f32x4 acc[4];
#pragma unroll
    for (int j = 0; j < 4; ++j) acc[j] = (f32x4){0.f, 0.f, 0.f, 0.f};
#pragma unroll
    for (int j = 0; j < 4; ++j) {
        acc[j] = __builtin_amdgcn_mfma_f32_16x16x32_bf16(af0, wf[j][0], acc[j], 0, 0, 0);
        acc[j] = __builtin_amdgcn_mfma_f32_16x16x32_bf16(af1, wf[j][1], acc[j], 0, 0, 0);
    }

#pragma unroll
    for (int j = 0; j < 4; ++j)
#pragma unroll
        for (int r = 0; r < 4; ++r)
            vlds[wave*16 + g*4 + r][j*16 + l16] = (__bf16)acc[j][r];
    __syncthreads();

    if (which < 2) {
        int row = t >> 2, seg = t & 3;
        __bf16* dst = (which == 0 ? qb : kb) + (size_t)nh*SEQ*64
                      + (size_t)(sblk*64 + row)*64 + seg*16;
        *reinterpret_cast<int4*>(dst)     = *reinterpret_cast<const int4*>(&vlds[row][seg*16]);
        *reinterpret_cast<int4*>(dst + 8) = *reinterpret_cast<const int4*>(&vlds[row][seg*16 + 8]);
    } else {
        int d = t & 63, sc4 = t >> 6;
        alignas(16) __bf16 tmp[16];
#pragma unroll
        for (int i = 0; i < 16; ++i) tmp[i] = vlds[sc4*16 + i][d];
        __bf16* dst = vtb + ((size_t)nh*64 + d)*SEQ + sblk*64 + sc4*16;
        *reinterpret_cast<int4*>(dst)     = *reinterpret_cast<const int4*>(tmp);
        *reinterpret_cast<int4*>(dst + 8) = *reinterpret_cast<const int4*>(tmp + 8);
    }
}

// ---------------------------------------------------------------------------
// Kernel 2: flash attention — SESSION-BEST VERIFIED (r9/r12: attn 72.7us,
// total 123us, absmax 4.9e-4). Half-tile software pipeline, per tile t
// (one unfenced scheduling region):
//   QKT(t,sb1)->y || SMPV(t,sb0 from X) || QKT(t+1,sb0)->Z || SMPV(t,sb1)
// Persistent-zero C-in on fresh QK^T chains. 4-deep LDS ring (64KB), one
// barrier/iter, counted vmcnt. X/Z ping-pong via 2x unrolled loop.
// grid = 512, block = 256 (4 waves, 64 q each), 2 blocks/CU.
//
// SESSION LEDGER (12 rounds; do not retry without NEW evidence):
//  - unfence + half-tile pipeline: +8% (the wins; r5/r6)
//  - r7 forced sched_group interleave: -9% (T19 null-as-graft holds)
//  - r8 wave-parity stagger: FAILED correctness (suspect: setprio/
//    sched_barrier in wave-divergent branches)
//  - r1 q-shrink occupancy: -8% (LDS reads scale inversely with q/wave)
//  - r2 LDS-free (L2-direct frags): -2x (loses 4-wave tile sharing)
//  - r4 cross-tile e-pipe: spilled (8 live f32x16 e-sets > 256 VGPR)
//  - r10/r11/r13 K-split x2 occupancy: FAILED x3 (6e-3 err x2, format-
//    independent; d_out-as-scratch crashed harness). Plumbing audited 3x,
//    bug never located.
// Residual state: MfmaUtil 40 / VALUBusy 47 / LDS ~40, sum ~ wall ->
// serialized pipes at 2 waves/SIMD; local minimum, not HW roofline.
// ---------------------------------------------------------------------------
__global__ __launch_bounds__(256, 2) void attn_kernel(
    const __bf16* __restrict__ qb, const __bf16* __restrict__ kb,
    const __bf16* __restrict__ vtb, __bf16* __restrict__ ob)
{
    __shared__ __align__(16) char smem[65536];

    int t = threadIdx.x;
    int wave = t >> 6, lane = t & 63;
    int l31 = lane & 31, hi = lane >> 5;

    int id = blockIdx.x;
    int qblk = id >> 6;
    int nh = (id & 7)*8 + ((id >> 3) & 7);
    int n = nh >> 4, h = nh & 15;

    const __bf16* Qp = qb  + (size_t)nh*SEQ*64;
    const __bf16* Kp = kb  + (size_t)nh*SEQ*64;
    const __bf16* Vp = vtb + (size_t)nh*64*SEQ;

    int st_row[2], st_col[2];
#pragma unroll
    for (int i = 0; i < 2; ++i) {
        int o = wave*2048 + i*1024 + lane*16;
        st_row[i] = o >> 7;
        st_col[i] = (o & 127) ^ ((st_row[i] & 7) << 4);
    }

    int q0 = qblk*256 + wave*64;
    const __bf16* qp = Qp + (size_t)(q0 + l31)*64 + hi*8;
    bf16x8 qfA[4], qfB[4];
#pragma unroll
    for (int i = 0; i < 4; ++i) {
        qfA[i] = *reinterpret_cast<const bf16x8*>(qp + i*16);
        qfB[i] = *reinterpret_cast<const bf16x8*>(qp + 2048 + i*16);
    }

    const f32x16 vzero = Z16;   // persistent zero C-in for fresh MFMA chains
    f32x16 oaccA0 = Z16, oaccA1 = Z16, oaccB0 = Z16, oaccB1 = Z16;
    float lsA0 = 0.f, lsA1 = 0.f, lsA2 = 0.f, lsA3 = 0.f;
    float lsB0 = 0.f, lsB1 = 0.f, lsB2 = 0.f, lsB3 = 0.f;

    const char* vb_;
    int swz = (l31 & 7) << 4;

#define STAGE_TILE(gbase, stride, ldsoff)                                          \
    {                                                                              \
        _Pragma("unroll")                                                          \
        for (int i_ = 0; i_ < 2; ++i_) {                                           \
            const char* g_ = (const char*)((gbase) + (size_t)st_row[i_]*(stride))  \
                             + st_col[i_];                                         \
            __builtin_amdgcn_global_load_lds(                                      \
                (const __attribute__((address_space(1))) void*)g_,                 \
                (__attribute__((address_space(3))) void*)(smem + (ldsoff)          \
                    + wave*2048 + i_*1024), 16, 0, 0);                             \
        }                                                                          \
    }

#define STAGE(s)                                                                   \
    {                                                                              \
        int b_ = (s) & 3;                                                          \
        STAGE_TILE(Kp + (size_t)(s)*64*64, 64, b_*8192);                           \
        STAGE_TILE(Vp + (size_t)(s)*64, SEQ, 32768 + b_*8192);                     \
    }

// QK^T half-tile: k-rows RO..RO+31 of buffer KBP, 8 MFMAs on 2 chains.
// First MFMA of each chain uses vzero C-in (no zero-init movs needed).
#define QKTH(KBP, RO, EA, EB)                                                      \
    {                                                                              \
        bf16x8 kf0_ = *(const bf16x8*)((KBP) + ((RO) + l31)*128 + ((0*32 + hi*16) ^ swz)); \
        bf16x8 kf1_ = *(const bf16x8*)((KBP) + ((RO) + l31)*128 + ((1*32 + hi*16) ^ swz)); \
        bf16x8 kf2_ = *(const bf16x8*)((KBP) + ((RO) + l31)*128 + ((2*32 + hi*16) ^ swz)); \
        bf16x8 kf3_ = *(const bf16x8*)((KBP) + ((RO) + l31)*128 + ((3*32 + hi*16) ^ swz)); \
        EA = __builtin_amdgcn_mfma_f32_32x32x16_bf16(kf0_, qfA[0], vzero, 0, 0, 0); \
        EB = __builtin_amdgcn_mfma_f32_32x32x16_bf16(kf0_, qfB[0], vzero, 0, 0, 0); \
        EA = __builtin_amdgcn_mfma_f32_32x32x16_bf16(kf1_, qfA[1], EA, 0, 0, 0);   \
        EB = __builtin_amdgcn_mfma_f32_32x32x16_bf16(kf1_, qfB[1], EB, 0, 0, 0);   \
        EA = __builtin_amdgcn_mfma_f32_32x32x16_bf16(kf2_, qfA[2], EA, 0, 0, 0);   \
        EB = __builtin_amdgcn_mfma_f32_32x32x16_bf16(kf2_, qfB[2], EB, 0, 0, 0);   \
        EA = __builtin_amdgcn_mfma_f32_32x32x16_bf16(kf3_, qfA[3], EA, 0, 0, 0);   \
        EB = __builtin_amdgcn_mfma_f32_32x32x16_bf16(kf3_, qfB[3], EB, 0, 0, 0);   \
    }

#define MAKE_PU_FAST(E, P, PU0, PU1)                                               \
    {                                                                              \
        _Pragma("unroll")                                                          \
        for (int i_ = 0; i_ < 16; ++i_)                                            \
            P[i_] = __builtin_amdgcn_exp2f(E[i_]);                                 \
        unsigned w00 = cvt_pk_bf16(P[0],  P[1]);                                   \
        unsigned w01 = cvt_pk_bf16(P[2],  P[3]);                                   \
        unsigned w10 = cvt_pk_bf16(P[4],  P[5]);                                   \
        unsigned w11 = cvt_pk_bf16(P[6],  P[7]);                                   \
        unsigned w20 = cvt_pk_bf16(P[8],  P[9]);                                   \
        unsigned w21 = cvt_pk_bf16(P[10], P[11]);                                  \
        unsigned w30 = cvt_pk_bf16(P[12], P[13]);                                  \
        unsigned w31 = cvt_pk_bf16(P[14], P[15]);                                  \
        pl_swap(w00, w10); pl_swap(w01, w11);                                      \
        pl_swap(w20, w30); pl_swap(w21, w31);                                      \
        PU0.u[0] = w00; PU0.u[1] = w01; PU0.u[2] = w10; PU0.u[3] = w11;            \
        PU1.u[0] = w20; PU1.u[1] = w21; PU1.u[2] = w30; PU1.u[3] = w31;            \
    }

#define LS_ACC(P, LS0, LS1, LS2, LS3)                                              \
    {                                                                              \
        LS0 += P[0] + P[4];  LS1 += P[1] + P[5];                                   \
        LS2 += P[2] + P[6];  LS3 += P[3] + P[7];                                   \
        LS0 += P[8] + P[12]; LS1 += P[9] + P[13];                                  \
        LS2 += P[10] + P[14]; LS3 += P[11] + P[15];                                \
    }

#define SMPV(SB, EA, EB)                                                           \
    {                                                                              \
        union { unsigned u[4]; bf16x8 v; } puA0, puA1, puB0, puB1;                 \
        float pA_[16], pB_[16];                                                    \
        MAKE_PU_FAST(EA, pA_, puA0, puA1)                                          \
        MAKE_PU_FAST(EB, pB_, puB0, puB1)                                          \
        bf16x8 v00 = *(const bf16x8*)(vb_ + (l31)*128      + (((SB)*64 +  0 + hi*16) ^ swz)); \
        bf16x8 v01 = *(const bf16x8*)(vb_ + (l31)*128      + (((SB)*64 + 32 + hi*16) ^ swz)); \
        bf16x8 v10 = *(const bf16x8*)(vb_ + (32 + l31)*128 + (((SB)*64 +  0 + hi*16) ^ swz)); \
        bf16x8 v11 = *(const bf16x8*)(vb_ + (32 + l31)*128 + (((SB)*64 + 32 + hi*16) ^ swz)); \
        oaccA0 = __builtin_amdgcn_mfma_f32_32x32x16_bf16(v00, puA0.v, oaccA0, 0, 0, 0); \
        oaccA1 = __builtin_amdgcn_mfma_f32_32x32x16_bf16(v10, puA0.v, oaccA1, 0, 0, 0); \
        oaccB0 = __builtin_amdgcn_mfma_f32_32x32x16_bf16(v00, puB0.v, oaccB0, 0, 0, 0); \
        oaccB1 = __builtin_amdgcn_mfma_f32_32x32x16_bf16(v10, puB0.v, oaccB1, 0, 0, 0); \
        oaccA0 = __builtin_amdgcn_mfma_f32_32x32x16_bf16(v01, puA1.v, oaccA0, 0, 0, 0); \
        oaccA1 = __builtin_amdgcn_mfma_f32_32x32x16_bf16(v11, puA1.v, oaccA1, 0, 0, 0); \
        oaccB0 = __builtin_amdgcn_mfma_f32_32x32x16_bf16(v01, puB1.v, oaccB0, 0, 0, 0); \
        oaccB1 = __builtin_amdgcn_mfma_f32_32x32x16_bf16(v11, puB1.v, oaccB1, 0, 0, 0); \
        LS_ACC(pA_, lsA0, lsA1, lsA2, lsA3)                                        \
        LS_ACC(pB_, lsB0, lsB1, lsB2, lsB3)                                        \
    }

// One pipelined tile: consume e(T,sb0) from (XA,XB); produce e(T+1,sb0) into
// (ZA,ZB).  VMN = vmcnt after staging.  DO_STAGE: stage tile T+2.
#define BODY(T, XA, XB, ZA, ZB, DO_STAGE, VMN)                                     \
    {                                                                              \
        if (DO_STAGE) STAGE((T) + 2);                                              \
        asm volatile("s_waitcnt vmcnt(" #VMN ")" ::: "memory");                    \
        __builtin_amdgcn_s_barrier();                                              \
        __builtin_amdgcn_sched_barrier(0);                                         \
        const char* kcur_ = smem + ((T) & 3)*8192;                                 \
        const char* knxt_ = smem + (((T) + 1) & 3)*8192;                           \
        vb_ = smem + 32768 + ((T) & 3)*8192;                                       \
        f32x16 yA_, yB_;                                                           \
        QKTH(kcur_, 32, yA_, yB_)                                                  \
        SMPV(0, XA, XB)                                                            \
        QKTH(knxt_, 0, ZA, ZB)                                                     \
        SMPV(1, yA_, yB_)                                                          \
    }

    // prologue: stage tiles 0,1; then e(0,sb0) -> X
    STAGE(0);
    STAGE(1);
    asm volatile("s_waitcnt vmcnt(4)" ::: "memory");
    __builtin_amdgcn_s_barrier();
    __builtin_amdgcn_sched_barrier(0);
    f32x16 xA, xB;
    f32x16 zA, zB;
    QKTH(smem + 0, 0, xA, xB)

    // main: t = 0..29 in ping-pong pairs (always stages t+2 <= 31)
    for (int p = 0; p < 15; ++p) {
        int t0 = 2*p;
        BODY(t0,     xA, xB, zA, zB, 1, 4)
        BODY(t0 + 1, zA, zB, xA, xB, 1, 4)
    }
    // t = 30: no stage (t+2 == 32), drain to confirm tile 31
    BODY(30, xA, xB, zA, zB, 0, 0)

    // tail t = 31: consume Z (= e(31,sb0)), compute sb1, no next-QKT
    {
        asm volatile("s_waitcnt vmcnt(0)" ::: "memory");
        __builtin_amdgcn_s_barrier();
        __builtin_amdgcn_sched_barrier(0);
        const char* kcur_ = smem + (31 & 3)*8192;
        vb_ = smem + 32768 + (31 & 3)*8192;
        f32x16 yA_, yB_;
        QKTH(kcur_, 32, yA_, yB_)
        SMPV(0, zA, zB)
        SMPV(1, yA_, yB_)
    }

    float lA = (lsA0 + lsA1) + (lsA2 + lsA3);
    float totA = lA + __shfl_xor(lA, 32);
    float invA = 1.f / totA;
    float lB = (lsB0 + lsB1) + (lsB2 + lsB3);
    float totB = lB + __shfl_xor(lB, 32);
    float invB = 1.f / totB;

    __bf16* opA = ob + (size_t)(n*SEQ + q0 + l31)*EMB + h*64;
    __bf16* opB = opA + (size_t)32*EMB;
#pragma unroll
    for (int j = 0; j < 4; ++j)
#pragma unroll
        for (int c = 0; c < 4; ++c) {
            int d_ = c + 8*j + 4*hi;
            opA[d_]      = (__bf16)(oaccA0[4*j + c] * invA);
            opA[32 + d_] = (__bf16)(oaccA1[4*j + c] * invA);
            opB[d_]      = (__bf16)(oaccB0[4*j + c] * invB);
            opB[32 + d_] = (__bf16)(oaccB1[4*j + c] * invB);
        }
#undef STAGE_TILE
#undef STAGE
#undef QKTH
#undef MAKE_PU_FAST
#undef LS_ACC
#undef SMPV
#undef BODY
}

// ---------------------------------------------------------------------------
// Kernel 3: out = O @ Wo^T + bo. m97-pattern tiled GEMM.
// ---------------------------------------------------------------------------
__global__ __launch_bounds__(256, 2) void out_gemm_kernel(
    const __bf16* __restrict__ ob, const __bf16* __restrict__ wob,
    const float* __restrict__ bo, float* __restrict__ out)
{
    __shared__ __align__(16) char smem[65536];

    int t = threadIdx.x;
    int wave = t >> 6, lane = t & 63;
    int l16 = lane & 15, g = lane >> 4;

    int bid = blockIdx.x;
    int swz = (bid & 7)*64 + (bid >> 3);
    int mb = (swz >> 3)*128;
    int nb = (swz & 7)*128;
    int wr = wave >> 1, wc = wave & 1;

    int st_row[4], st_col[4];
#pragma unroll
    for (int i = 0; i < 4; ++i) {
        int o = i*4096 + wave*1024 + lane*16;
        st_row[i] = o >> 7;
        st_col[i] = (o & 127) ^ ((st_row[i] & 7) << 4);
    }

#define G_STAGE(kt, buf)                                                            \
    {                                                                               \
        _Pragma("unroll")                                                           \
        for (int i_ = 0; i_ < 4; ++i_) {                                            \
            const char* ga_ = (const char*)(ob + (size_t)(mb + st_row[i_])*EMB      \
                                + (kt)*64) + st_col[i_];                            \
            __builtin_amdgcn_global_load_lds(                                       \
                (const __attribute__((address_space(1))) void*)ga_,                 \
                (__attribute__((address_space(3))) void*)(smem + (buf)*16384        \
                    + i_*4096 + wave*1024), 16, 0, 0);                              \
            const char* gb_ = (const char*)(wob + (size_t)(nb + st_row[i_])*EMB     \
                                + (kt)*64) + st_col[i_];                            \
            __builtin_amdgcn_global_load_lds(                                       \
                (const __attribute__((address_space(1))) void*)gb_,                 \
                (__attribute__((address_space(3))) void*)(smem + 32768 + (buf)*16384\
                    + i_*4096 + wave*1024), 16, 0, 0);                              \
        }                                                                           \
    }

    f32x4 acc[4][4];
#pragma unroll
    for (int m = 0; m < 4; ++m)
#pragma unroll
        for (int n = 0; n < 4; ++n) acc[m][n] = (f32x4){0.f, 0.f, 0.f, 0.f};

    G_STAGE(0, 0);
    __syncthreads();

    int cur = 0;
    for (int kt = 0; kt < EMB/64; ++kt) {
        if (kt + 1 < EMB/64) G_STAGE(kt + 1, cur ^ 1);

        const char* ab_ = smem + cur*16384;
        const char* bb_ = smem + 32768 + cur*16384;

        bf16x8 af[4][2], bf[4][2];
#pragma unroll
        for (int m = 0; m < 4; ++m) {
            int row = wr*64 + m*16 + l16, s = (row & 7) << 4;
            af[m][0] = *(const bf16x8*)(ab_ + row*128 + ((g*16) ^ s));
            af[m][1] = *(const bf16x8*)(ab_ + row*128 + ((64 + g*16) ^ s));
        }
#pragma unroll
        for (int n = 0; n < 4; ++n) {
            int row = wc*64 + n*16 + l16, s = (row & 7) << 4;
            bf[n][0] = *(const bf16x8*)(bb_ + row*128 + ((g*16) ^ s));
            bf[n][1] = *(const bf16x8*)(bb_ + row*128 + ((64 + g*16) ^ s));
        }

        __builtin_amdgcn_s_setprio(1);
#pragma unroll
        for (int m = 0; m < 4; ++m)
#pragma unroll
            for (int n = 0; n < 4; ++n) {
                acc[m][n] = __builtin_amdgcn_mfma_f32_16x16x32_bf16(af[m][0], bf[n][0], acc[m][n], 0, 0, 0);
                acc[m][n] = __builtin_amdgcn_mfma_f32_16x16x32_bf16(af[m][1], bf[n][1], acc[m][n], 0, 0, 0);
            }
        __builtin_amdgcn_s_setprio(0);

        __syncthreads();
        cur ^= 1;
    }

#pragma unroll
    for (int n = 0; n < 4; ++n) {
        int col = nb + wc*64 + n*16 + l16;
        float bias = bo[col];
#pragma unroll
        for (int m = 0; m < 4; ++m) {
            int rowb = mb + wr*64 + m*16 + g*4;
#pragma unroll
            for (int r = 0; r < 4; ++r)
                out[(size_t)(rowb + r)*EMB + col] = acc[m][n][r] + bias;
        }
    }
#undef G_STAGE
}

extern "C" void kernel_launch(void* const* d_in, const int* in_sizes, int n_in,
                              void* d_out, int out_size, void* d_ws, size_t ws_size,
                              hipStream_t stream) {
    const float* keys   = (const float*)d_in[0];
    const float* query  = (const float*)d_in[1];
    const float* values = (const float*)d_in[2];
    const float* Wk     = (const float*)d_in[3];
    const float* Wq     = (const float*)d_in[4];
    const float* Wv     = (const float*)d_in[5];
    const float* Wo     = (const float*)d_in[6];
    const float* bo     = (const float*)d_in[7];
    float* out = (float*)d_out;

    char* ws = (char*)d_ws;
    __bf16* qb  = (__bf16*)(ws);                              // 16 MB [n,h,s,64] (pre-scaled)
    __bf16* kb  = (__bf16*)(ws + (size_t)16*1024*1024);       // 16 MB [n,h,s,64]
    __bf16* vtb = (__bf16*)(ws + (size_t)32*1024*1024);       // 16 MB [n,h,64,s]
    __bf16* ob  = (__bf16*)(ws + (size_t)48*1024*1024);       // 16 MB [n*s, 1024]
    __bf16* wob = (__bf16*)(ws + (size_t)64*1024*1024);       //  2 MB [1024,1024]

    hipLaunchKernelGGL(proj_kernel, dim3(SEQ/64, NBATCH*HEADS, 4), dim3(256), 0, stream,
                       keys, query, values, Wk, Wq, Wv, Wo, qb, kb, vtb, wob);
    hipLaunchKernelGGL(attn_kernel, dim3(512), dim3(256), 0, stream,
                       qb, kb, vtb, ob);
    hipLaunchKernelGGL(out_gemm_kernel, dim3(512), dim3(256), 0, stream,
                       ob, wob, bo, out);
}

// Round 15
// 122.346 us; speedup vs baseline: 1.0067x; 1.0026x over previous
//
#include <hip/hip_runtime.h>
#include <hip/hip_bf16.h>

#define HEADS 16
#define HDIM 64
#define EMB 1024
#define NBATCH 4
#define SEQ 2048
#define NT (SEQ/64)

typedef __bf16 bf16x8 __attribute__((ext_vector_type(8)));
typedef __bf16 bf16x4 __attribute__((ext_vector_type(4)));
typedef float f32x4 __attribute__((ext_vector_type(4)));
typedef float f32x16 __attribute__((ext_vector_type(16)));

#define Z16 {0.f,0.f,0.f,0.f,0.f,0.f,0.f,0.f,0.f,0.f,0.f,0.f,0.f,0.f,0.f,0.f}

static __device__ __forceinline__ bf16x8 load_cvt8(const float* __restrict__ p) {
    float4 a = *reinterpret_cast<const float4*>(p);
    float4 b = *reinterpret_cast<const float4*>(p + 4);
    bf16x8 r;
    r[0] = (__bf16)a.x; r[1] = (__bf16)a.y; r[2] = (__bf16)a.z; r[3] = (__bf16)a.w;
    r[4] = (__bf16)b.x; r[5] = (__bf16)b.y; r[6] = (__bf16)b.z; r[7] = (__bf16)b.w;
    return r;
}

static __device__ __forceinline__ unsigned cvt_pk_bf16(float a, float b) {
    unsigned d;
    asm("v_cvt_pk_bf16_f32 %0, %1, %2" : "=v"(d) : "v"(a), "v"(b));
    return d;
}

static __device__ __forceinline__ void pl_swap(unsigned &a, unsigned &b) {
#if __has_builtin(__builtin_amdgcn_permlane32_swap)
    auto r = __builtin_amdgcn_permlane32_swap((int)a, (int)b, false, false);
    a = (unsigned)r[0]; b = (unsigned)r[1];
#else
    asm("v_permlane32_swap_b32 %0, %1" : "+v"(a), "+v"(b));
#endif
}

// ---------------------------------------------------------------------------
// Kernel 1: QKV projection + Wo convert. grid=(SEQ/64, N*H, 4), 256 thr.
// z==0: q = (query @ Wq^T) * log2e/512 -> qb; z==1: k; z==2: v -> vtb (transp)
// z==3: Wo fp32->bf16.
// ---------------------------------------------------------------------------
__global__ __launch_bounds__(256) void proj_kernel(
    const float* __restrict__ keys, const float* __restrict__ query,
    const float* __restrict__ values,
    const float* __restrict__ Wk, const float* __restrict__ Wq,
    const float* __restrict__ Wv, const float* __restrict__ Wo,
    __bf16* __restrict__ qb, __bf16* __restrict__ kb, __bf16* __restrict__ vtb,
    __bf16* __restrict__ wob)
{
    int t = threadIdx.x;
    int which = blockIdx.z;

    if (which == 3) {
        int idx = blockIdx.y*gridDim.x + blockIdx.x;
        if (idx < EMB*EMB/4/256) {
            int i = idx*256 + t;
            float4 v = reinterpret_cast<const float4*>(Wo)[i];
            bf16x4 r;
            r[0] = (__bf16)v.x; r[1] = (__bf16)v.y; r[2] = (__bf16)v.z; r[3] = (__bf16)v.w;
            reinterpret_cast<bf16x4*>(wob)[i] = r;
        }
        return;
    }

    __shared__ __align__(16) __bf16 vlds[64][72];

    int wave = t >> 6, lane = t & 63;
    int l16 = lane & 15, g = lane >> 4;
    int sblk = blockIdx.x, nh = blockIdx.y;
    int n = nh >> 4, h = nh & 15;

    const float* X = (which == 0) ? query : (which == 1) ? keys : values;
    const float* W = (which == 0) ? Wq    : (which == 1) ? Wk   : Wv;
    const float wsc = (which == 0) ? (1.44269504088896f / 512.f) : 1.0f;

    {
        const float* wp = W + t*16;
        int row = t >> 2, c0 = (t & 3)*16;
#pragma unroll
        for (int q4 = 0; q4 < 4; ++q4) {
            float4 v = *reinterpret_cast<const float4*>(wp + q4*4);
            vlds[row][c0 + q4*4 + 0] = (__bf16)(v.x*wsc);
            vlds[row][c0 + q4*4 + 1] = (__bf16)(v.y*wsc);
            vlds[row][c0 + q4*4 + 2] = (__bf16)(v.z*wsc);
            vlds[row][c0 + q4*4 + 3] = (__bf16)(v.w*wsc);
        }
    }
    __syncthreads();

    bf16x8 wf[4][2];
#pragma unroll
    for (int j = 0; j < 4; ++j)
#pragma unroll
        for (int kc = 0; kc < 2; ++kc)
            wf[j][kc] = *reinterpret_cast<const bf16x8*>(&vlds[j*16 + l16][kc*32 + g*8]);

    int s0 = sblk*64 + wave*16;
    const float* xp = X + ((size_t)(n*SEQ + s0 + l16)*HEADS + h)*64;
    bf16x8 af0 = load_cvt8(xp + g*8);
    bf16x8 af1 = load_cvt8(xp + 32 + g*8);

    __syncthreads();

    f32x4 acc[4];
#pragma unroll
    for (int j = 0; j < 4; ++j) acc[j] = (f32x4){0.f, 0.f, 0.f, 0.f};
#pragma unroll
    for (int j = 0; j < 4; ++j) {
        acc[j] = __builtin_amdgcn_mfma_f32_16x16x32_bf16(af0, wf[j][0], acc[j], 0, 0, 0);
        acc[j] = __builtin_amdgcn_mfma_f32_16x16x32_bf16(af1, wf[j][1], acc[j], 0, 0, 0);
    }

#pragma unroll
    for (int j = 0; j < 4; ++j)
#pragma unroll
        for (int r = 0; r < 4; ++r)
            vlds[wave*16 + g*4 + r][j*16 + l16] = (__bf16)acc[j][r];
    __syncthreads();

    if (which < 2) {
        int row = t >> 2, seg = t & 3;
        __bf16* dst = (which == 0 ? qb : kb) + (size_t)nh*SEQ*64
                      + (size_t)(sblk*64 + row)*64 + seg*16;
        *reinterpret_cast<int4*>(dst)     = *reinterpret_cast<const int4*>(&vlds[row][seg*16]);
        *reinterpret_cast<int4*>(dst + 8) = *reinterpret_cast<const int4*>(&vlds[row][seg*16 + 8]);
    } else {
        int d = t & 63, sc4 = t >> 6;
        alignas(16) __bf16 tmp[16];
#pragma unroll
        for (int i = 0; i < 16; ++i) tmp[i] = vlds[sc4*16 + i][d];
        __bf16* dst = vtb + ((size_t)nh*64 + d)*SEQ + sblk*64 + sc4*16;
        *reinterpret_cast<int4*>(dst)     = *reinterpret_cast<const int4*>(tmp);
        *reinterpret_cast<int4*>(dst + 8) = *reinterpret_cast<const int4*>(tmp + 8);
    }
}

// ---------------------------------------------------------------------------
// Kernel 2: flash attention — r9 structure + CROSS-BLOCK PHASE SEEDING.
// The two co-resident blocks per CU are not barrier-synced; their phase
// offset is neutral-stable (in-phase and anti-phase both self-sustaining),
// and dispatch seeds zero offset -> convoyed pipes (MfmaUtil 40 + VALU 46,
// serialized). Fix: blocks with bit 8 set sleep ~half an iteration (2752cy)
// AFTER issuing the prologue stages (loads in flight during sleep). Blocks
// b and b+256 are expected to share a CU (512 blocks round-robin 8 XCDs x
// 32 CUs). Pure time shift: zero semantic change, +1.1us tail if null.
//
// SESSION LEDGER (do not retry without NEW evidence):
//  - unfence + half-tile pipeline: +8% (r5/r6, the wins)
//  - r7 forced sched_group interleave: -9%
//  - r8 intra-block wave stagger: FAILED correctness
//  - r1 q-shrink / r2 LDS-free / r4 cross-tile e-pipe: regressions
//  - r10/r11/r13 K-split: FAILED x3 (bug never located)
// ---------------------------------------------------------------------------
__global__ __launch_bounds__(256, 2) void attn_kernel(
    const __bf16* __restrict__ qb, const __bf16* __restrict__ kb,
    const __bf16* __restrict__ vtb, __bf16* __restrict__ ob)
{
    __shared__ __align__(16) char smem[65536];

    int t = threadIdx.x;
    int wave = t >> 6, lane = t & 63;
    int l31 = lane & 31, hi = lane >> 5;

    int id = blockIdx.x;
    int qblk = id >> 6;
    int nh = (id & 7)*8 + ((id >> 3) & 7);
    int n = nh >> 4, h = nh & 15;

    const __bf16* Qp = qb  + (size_t)nh*SEQ*64;
    const __bf16* Kp = kb  + (size_t)nh*SEQ*64;
    const __bf16* Vp = vtb + (size_t)nh*64*SEQ;

    int st_row[2], st_col[2];
#pragma unroll
    for (int i = 0; i < 2; ++i) {
        int o = wave*2048 + i*1024 + lane*16;
        st_row[i] = o >> 7;
        st_col[i] = (o & 127) ^ ((st_row[i] & 7) << 4);
    }

    int q0 = qblk*256 + wave*64;
    const __bf16* qp = Qp + (size_t)(q0 + l31)*64 + hi*8;
    bf16x8 qfA[4], qfB[4];
#pragma unroll
    for (int i = 0; i < 4; ++i) {
        qfA[i] = *reinterpret_cast<const bf16x8*>(qp + i*16);
        qfB[i] = *reinterpret_cast<const bf16x8*>(qp + 2048 + i*16);
    }

    const f32x16 vzero = Z16;   // persistent zero C-in for fresh MFMA chains
    f32x16 oaccA0 = Z16, oaccA1 = Z16, oaccB0 = Z16, oaccB1 = Z16;
    float lsA0 = 0.f, lsA1 = 0.f, lsA2 = 0.f, lsA3 = 0.f;
    float lsB0 = 0.f, lsB1 = 0.f, lsB2 = 0.f, lsB3 = 0.f;

    const char* vb_;
    int swz = (l31 & 7) << 4;

#define STAGE_TILE(gbase, stride, ldsoff)                                          \
    {                                                                              \
        _Pragma("unroll")                                                          \
        for (int i_ = 0; i_ < 2; ++i_) {                                           \
            const char* g_ = (const char*)((gbase) + (size_t)st_row[i_]*(stride))  \
                             + st_col[i_];                                         \
            __builtin_amdgcn_global_load_lds(                                      \
                (const __attribute__((address_space(1))) void*)g_,                 \
                (__attribute__((address_space(3))) void*)(smem + (ldsoff)          \
                    + wave*2048 + i_*1024), 16, 0, 0);                             \
        }                                                                          \
    }

#define STAGE(s)                                                                   \
    {                                                                              \
        int b_ = (s) & 3;                                                          \
        STAGE_TILE(Kp + (size_t)(s)*64*64, 64, b_*8192);                           \
        STAGE_TILE(Vp + (size_t)(s)*64, SEQ, 32768 + b_*8192);                     \
    }

// QK^T half-tile: k-rows RO..RO+31 of buffer KBP, 8 MFMAs on 2 chains.
// First MFMA of each chain uses vzero C-in (no zero-init movs needed).
#define QKTH(KBP, RO, EA, EB)                                                      \
    {                                                                              \
        bf16x8 kf0_ = *(const bf16x8*)((KBP) + ((RO) + l31)*128 + ((0*32 + hi*16) ^ swz)); \
        bf16x8 kf1_ = *(const bf16x8*)((KBP) + ((RO) + l31)*128 + ((1*32 + hi*16) ^ swz)); \
        bf16x8 kf2_ = *(const bf16x8*)((KBP) + ((RO) + l31)*128 + ((2*32 + hi*16) ^ swz)); \
        bf16x8 kf3_ = *(const bf16x8*)((KBP) + ((RO) + l31)*128 + ((3*32 + hi*16) ^ swz)); \
        EA = __builtin_amdgcn_mfma_f32_32x32x16_bf16(kf0_, qfA[0], vzero, 0, 0, 0); \
        EB = __builtin_amdgcn_mfma_f32_32x32x16_bf16(kf0_, qfB[0], vzero, 0, 0, 0); \
        EA = __builtin_amdgcn_mfma_f32_32x32x16_bf16(kf1_, qfA[1], EA, 0, 0, 0);   \
        EB = __builtin_amdgcn_mfma_f32_32x32x16_bf16(kf1_, qfB[1], EB, 0, 0, 0);   \
        EA = __builtin_amdgcn_mfma_f32_32x32x16_bf16(kf2_, qfA[2], EA, 0, 0, 0);   \
        EB = __builtin_amdgcn_mfma_f32_32x32x16_bf16(kf2_, qfB[2], EB, 0, 0, 0);   \
        EA = __builtin_amdgcn_mfma_f32_32x32x16_bf16(kf3_, qfA[3], EA, 0, 0, 0);   \
        EB = __builtin_amdgcn_mfma_f32_32x32x16_bf16(kf3_, qfB[3], EB, 0, 0, 0);   \
    }

#define MAKE_PU_FAST(E, P, PU0, PU1)                                               \
    {                                                                              \
        _Pragma("unroll")                                                          \
        for (int i_ = 0; i_ < 16; ++i_)                                            \
            P[i_] = __builtin_amdgcn_exp2f(E[i_]);                                 \
        unsigned w00 = cvt_pk_bf16(P[0],  P[1]);                                   \
        unsigned w01 = cvt_pk_bf16(P[2],  P[3]);                                   \
        unsigned w10 = cvt_pk_bf16(P[4],  P[5]);                                   \
        unsigned w11 = cvt_pk_bf16(P[6],  P[7]);                                   \
        unsigned w20 = cvt_pk_bf16(P[8],  P[9]);                                   \
        unsigned w21 = cvt_pk_bf16(P[10], P[11]);                                  \
        unsigned w30 = cvt_pk_bf16(P[12], P[13]);                                  \
        unsigned w31 = cvt_pk_bf16(P[14], P[15]);                                  \
        pl_swap(w00, w10); pl_swap(w01, w11);                                      \
        pl_swap(w20, w30); pl_swap(w21, w31);                                      \
        PU0.u[0] = w00; PU0.u[1] = w01; PU0.u[2] = w10; PU0.u[3] = w11;            \
        PU1.u[0] = w20; PU1.u[1] = w21; PU1.u[2] = w30; PU1.u[3] = w31;            \
    }

#define LS_ACC(P, LS0, LS1, LS2, LS3)                                              \
    {                                                                              \
        LS0 += P[0] + P[4];  LS1 += P[1] + P[5];                                   \
        LS2 += P[2] + P[6];  LS3 += P[3] + P[7];                                   \
        LS0 += P[8] + P[12]; LS1 += P[9] + P[13];                                  \
        LS2 += P[10] + P[14]; LS3 += P[11] + P[15];                                \
    }

#define SMPV(SB, EA, EB)                                                           \
    {                                                                              \
        union { unsigned u[4]; bf16x8 v; } puA0, puA1, puB0, puB1;                 \
        float pA_[16], pB_[16];                                                    \
        MAKE_PU_FAST(EA, pA_, puA0, puA1)                                          \
        MAKE_PU_FAST(EB, pB_, puB0, puB1)                                          \
        bf16x8 v00 = *(const bf16x8*)(vb_ + (l31)*128      + (((SB)*64 +  0 + hi*16) ^ swz)); \
        bf16x8 v01 = *(const bf16x8*)(vb_ + (l31)*128      + (((SB)*64 + 32 + hi*16) ^ swz)); \
        bf16x8 v10 = *(const bf16x8*)(vb_ + (32 + l31)*128 + (((SB)*64 +  0 + hi*16) ^ swz)); \
        bf16x8 v11 = *(const bf16x8*)(vb_ + (32 + l31)*128 + (((SB)*64 + 32 + hi*16) ^ swz)); \
        oaccA0 = __builtin_amdgcn_mfma_f32_32x32x16_bf16(v00, puA0.v, oaccA0, 0, 0, 0); \
        oaccA1 = __builtin_amdgcn_mfma_f32_32x32x16_bf16(v10, puA0.v, oaccA1, 0, 0, 0); \
        oaccB0 = __builtin_amdgcn_mfma_f32_32x32x16_bf16(v00, puB0.v, oaccB0, 0, 0, 0); \
        oaccB1 = __builtin_amdgcn_mfma_f32_32x32x16_bf16(v10, puB0.v, oaccB1, 0, 0, 0); \
        oaccA0 = __builtin_amdgcn_mfma_f32_32x32x16_bf16(v01, puA1.v, oaccA0, 0, 0, 0); \
        oaccA1 = __builtin_amdgcn_mfma_f32_32x32x16_bf16(v11, puA1.v, oaccA1, 0, 0, 0); \
        oaccB0 = __builtin_amdgcn_mfma_f32_32x32x16_bf16(v01, puB1.v, oaccB0, 0, 0, 0); \
        oaccB1 = __builtin_amdgcn_mfma_f32_32x32x16_bf16(v11, puB1.v, oaccB1, 0, 0, 0); \
        LS_ACC(pA_, lsA0, lsA1, lsA2, lsA3)                                        \
        LS_ACC(pB_, lsB0, lsB1, lsB2, lsB3)                                        \
    }

// One pipelined tile: consume e(T,sb0) from (XA,XB); produce e(T+1,sb0) into
// (ZA,ZB).  VMN = vmcnt after staging.  DO_STAGE: stage tile T+2.
#define BODY(T, XA, XB, ZA, ZB, DO_STAGE, VMN)                                     \
    {                                                                              \
        if (DO_STAGE) STAGE((T) + 2);                                              \
        asm volatile("s_waitcnt vmcnt(" #VMN ")" ::: "memory");                    \
        __builtin_amdgcn_s_barrier();                                              \
        __builtin_amdgcn_sched_barrier(0);                                         \
        const char* kcur_ = smem + ((T) & 3)*8192;                                 \
        const char* knxt_ = smem + (((T) + 1) & 3)*8192;                           \
        vb_ = smem + 32768 + ((T) & 3)*8192;                                       \
        f32x16 yA_, yB_;                                                           \
        QKTH(kcur_, 32, yA_, yB_)                                                  \
        SMPV(0, XA, XB)                                                            \
        QKTH(knxt_, 0, ZA, ZB)                                                     \
        SMPV(1, yA_, yB_)                                                          \
    }

    // prologue: stage tiles 0,1 (loads in flight during any phase-seed sleep)
    STAGE(0);
    STAGE(1);

    // CROSS-BLOCK PHASE SEED: half the block population (expected CU-partner
    // parity: bit 8 of blockIdx under 8-XCD x 32-CU round-robin) delays
    // ~half an iteration (64*43 ~= 2752 cyc). Wave-uniform, pre-loop, no
    // semantic effect; offset is neutral-stable thereafter.
    if ((blockIdx.x >> 8) & 1)
        __builtin_amdgcn_s_sleep(43);

    asm volatile("s_waitcnt vmcnt(4)" ::: "memory");
    __builtin_amdgcn_s_barrier();
    __builtin_amdgcn_sched_barrier(0);
    f32x16 xA, xB;
    f32x16 zA, zB;
    QKTH(smem + 0, 0, xA, xB)

    // main: t = 0..29 in ping-pong pairs (always stages t+2 <= 31)
    for (int p = 0; p < 15; ++p) {
        int t0 = 2*p;
        BODY(t0,     xA, xB, zA, zB, 1, 4)
        BODY(t0 + 1, zA, zB, xA, xB, 1, 4)
    }
    // t = 30: no stage (t+2 == 32), drain to confirm tile 31
    BODY(30, xA, xB, zA, zB, 0, 0)

    // tail t = 31: consume Z (= e(31,sb0)), compute sb1, no next-QKT
    {
        asm volatile("s_waitcnt vmcnt(0)" ::: "memory");
        __builtin_amdgcn_s_barrier();
        __builtin_amdgcn_sched_barrier(0);
        const char* kcur_ = smem + (31 & 3)*8192;
        vb_ = smem + 32768 + (31 & 3)*8192;
        f32x16 yA_, yB_;
        QKTH(kcur_, 32, yA_, yB_)
        SMPV(0, zA, zB)
        SMPV(1, yA_, yB_)
    }

    float lA = (lsA0 + lsA1) + (lsA2 + lsA3);
    float totA = lA + __shfl_xor(lA, 32);
    float invA = 1.f / totA;
    float lB = (lsB0 + lsB1) + (lsB2 + lsB3);
    float totB = lB + __shfl_xor(lB, 32);
    float invB = 1.f / totB;

    __bf16* opA = ob + (size_t)(n*SEQ + q0 + l31)*EMB + h*64;
    __bf16* opB = opA + (size_t)32*EMB;
#pragma unroll
    for (int j = 0; j < 4; ++j)
#pragma unroll
        for (int c = 0; c < 4; ++c) {
            int d_ = c + 8*j + 4*hi;
            opA[d_]      = (__bf16)(oaccA0[4*j + c] * invA);
            opA[32 + d_] = (__bf16)(oaccA1[4*j + c] * invA);
            opB[d_]      = (__bf16)(oaccB0[4*j + c] * invB);
            opB[32 + d_] = (__bf16)(oaccB1[4*j + c] * invB);
        }
#undef STAGE_TILE
#undef STAGE
#undef QKTH
#undef MAKE_PU_FAST
#undef LS_ACC
#undef SMPV
#undef BODY
}

// ---------------------------------------------------------------------------
// Kernel 3: out = O @ Wo^T + bo. m97-pattern tiled GEMM.
// ---------------------------------------------------------------------------
__global__ __launch_bounds__(256, 2) void out_gemm_kernel(
    const __bf16* __restrict__ ob, const __bf16* __restrict__ wob,
    const float* __restrict__ bo, float* __restrict__ out)
{
    __shared__ __align__(16) char smem[65536];

    int t = threadIdx.x;
    int wave = t >> 6, lane = t & 63;
    int l16 = lane & 15, g = lane >> 4;

    int bid = blockIdx.x;
    int swz = (bid & 7)*64 + (bid >> 3);
    int mb = (swz >> 3)*128;
    int nb = (swz & 7)*128;
    int wr = wave >> 1, wc = wave & 1;

    int st_row[4], st_col[4];
#pragma unroll
    for (int i = 0; i < 4; ++i) {
        int o = i*4096 + wave*1024 + lane*16;
        st_row[i] = o >> 7;
        st_col[i] = (o & 127) ^ ((st_row[i] & 7) << 4);
    }

#define G_STAGE(kt, buf)                                                            \
    {                                                                               \
        _Pragma("unroll")                                                           \
        for (int i_ = 0; i_ < 4; ++i_) {                                            \
            const char* ga_ = (const char*)(ob + (size_t)(mb + st_row[i_])*EMB      \
                                + (kt)*64) + st_col[i_];                            \
            __builtin_amdgcn_global_load_lds(                                       \
                (const __attribute__((address_space(1))) void*)ga_,                 \
                (__attribute__((address_space(3))) void*)(smem + (buf)*16384        \
                    + i_*4096 + wave*1024), 16, 0, 0);                              \
            const char* gb_ = (const char*)(wob + (size_t)(nb + st_row[i_])*EMB     \
                                + (kt)*64) + st_col[i_];                            \
            __builtin_amdgcn_global_load_lds(                                       \
                (const __attribute__((address_space(1))) void*)gb_,                 \
                (__attribute__((address_space(3))) void*)(smem + 32768 + (buf)*16384\
                    + i_*4096 + wave*1024), 16, 0, 0);                              \
        }                                                                           \
    }

    f32x4 acc[4][4];
#pragma unroll
    for (int m = 0; m < 4; ++m)
#pragma unroll
        for (int n = 0; n < 4; ++n) acc[m][n] = (f32x4){0.f, 0.f, 0.f, 0.f};

    G_STAGE(0, 0);
    __syncthreads();

    int cur = 0;
    for (int kt = 0; kt < EMB/64; ++kt) {
        if (kt + 1 < EMB/64) G_STAGE(kt + 1, cur ^ 1);

        const char* ab_ = smem + cur*16384;
        const char* bb_ = smem + 32768 + cur*16384;

        bf16x8 af[4][2], bf[4][2];
#pragma unroll
        for (int m = 0; m < 4; ++m) {
            int row = wr*64 + m*16 + l16, s = (row & 7) << 4;
            af[m][0] = *(const bf16x8*)(ab_ + row*128 + ((g*16) ^ s));
            af[m][1] = *(const bf16x8*)(ab_ + row*128 + ((64 + g*16) ^ s));
        }
#pragma unroll
        for (int n = 0; n < 4; ++n) {
            int row = wc*64 + n*16 + l16, s = (row & 7) << 4;
            bf[n][0] = *(const bf16x8*)(bb_ + row*128 + ((g*16) ^ s));
            bf[n][1] = *(const bf16x8*)(bb_ + row*128 + ((64 + g*16) ^ s));
        }

        __builtin_amdgcn_s_setprio(1);
#pragma unroll
        for (int m = 0; m < 4; ++m)
#pragma unroll
            for (int n = 0; n < 4; ++n) {
                acc[m][n] = __builtin_amdgcn_mfma_f32_16x16x32_bf16(af[m][0], bf[n][0], acc[m][n], 0, 0, 0);
                acc[m][n] = __builtin_amdgcn_mfma_f32_16x16x32_bf16(af[m][1], bf[n][1], acc[m][n], 0, 0, 0);
            }
        __builtin_amdgcn_s_setprio(0);

        __syncthreads();
        cur ^= 1;
    }

#pragma unroll
    for (int n = 0; n < 4; ++n) {
        int col = nb + wc*64 + n*16 + l16;
        float bias = bo[col];
#pragma unroll
        for (int m = 0; m < 4; ++m) {
            int rowb = mb + wr*64 + m*16 + g*4;
#pragma unroll
            for (int r = 0; r < 4; ++r)
                out[(size_t)(rowb + r)*EMB + col] = acc[m][n][r] + bias;
        }
    }
#undef G_STAGE
}

extern "C" void kernel_launch(void* const* d_in, const int* in_sizes, int n_in,
                              void* d_out, int out_size, void* d_ws, size_t ws_size,
                              hipStream_t stream) {
    const float* keys   = (const float*)d_in[0];
    const float* query  = (const float*)d_in[1];
    const float* values = (const float*)d_in[2];
    const float* Wk     = (const float*)d_in[3];
    const float* Wq     = (const float*)d_in[4];
    const float* Wv     = (const float*)d_in[5];
    const float* Wo     = (const float*)d_in[6];
    const float* bo     = (const float*)d_in[7];
    float* out = (float*)d_out;

    char* ws = (char*)d_ws;
    __bf16* qb  = (__bf16*)(ws);                              // 16 MB [n,h,s,64] (pre-scaled)
    __bf16* kb  = (__bf16*)(ws + (size_t)16*1024*1024);       // 16 MB [n,h,s,64]
    __bf16* vtb = (__bf16*)(ws + (size_t)32*1024*1024);       // 16 MB [n,h,64,s]
    __bf16* ob  = (__bf16*)(ws + (size_t)48*1024*1024);       // 16 MB [n*s, 1024]
    __bf16* wob = (__bf16*)(ws + (size_t)64*1024*1024);       //  2 MB [1024,1024]

    hipLaunchKernelGGL(proj_kernel, dim3(SEQ/64, NBATCH*HEADS, 4), dim3(256), 0, stream,
                       keys, query, values, Wk, Wq, Wv, Wo, qb, kb, vtb, wob);
    hipLaunchKernelGGL(attn_kernel, dim3(512), dim3(256), 0, stream,
                       qb, kb, vtb, ob);
    hipLaunchKernelGGL(out_gemm_kernel, dim3(512), dim3(256), 0, stream,
                       ob, wob, bo, out);
}